// Round 1
// baseline (93.642 us; speedup 1.0000x reference)
//
#include <hip/hip_runtime.h>

#define EPS 1e-5f

typedef float f32x4 __attribute__((ext_vector_type(4)));
typedef short bf16x8 __attribute__((ext_vector_type(8)));

__device__ __forceinline__ unsigned short f2bf(float f) {
  unsigned int u = __builtin_bit_cast(unsigned int, f);
  u = (u + 0x7FFFu + ((u >> 16) & 1u)) >> 16;
  return (unsigned short)u;
}
__device__ __forceinline__ float bf2f(unsigned short h) {
  unsigned int u = ((unsigned int)h) << 16;
  return __builtin_bit_cast(float, u);
}

// ---------------------------------------------------------------------------
// Prep: fold BN into weights, build w2 in MFMA A-fragment layout (bf16).
// w2f[t], t = ((ks*16 + ct)*64 + lane)*8 + j  <->  A[ch = ct*16 + (lane&15)]
//                                                  [k  = ks*32 + (lane>>4)*8 + j]
// K padded 528 -> 544 with zeros.
// ---------------------------------------------------------------------------
__global__ __launch_bounds__(256) void k_prep(
    const float* __restrict__ w1, const float* __restrict__ b1,
    const float* __restrict__ g1, const float* __restrict__ be1,
    const float* __restrict__ m1, const float* __restrict__ v1,
    const float* __restrict__ w2, const float* __restrict__ b2,
    const float* __restrict__ g2, const float* __restrict__ be2,
    const float* __restrict__ m2, const float* __restrict__ v2,
    float* __restrict__ w1f, float* __restrict__ beta1,
    float* __restrict__ beta2, unsigned short* __restrict__ w2f)
{
  int t = blockIdx.x * 256 + threadIdx.x;
  if (t < 139264) {
    int j = t & 7, l = (t >> 3) & 63, ctks = t >> 9;
    int ct = ctks & 15, ks = ctks >> 4;
    int k = ks * 32 + (l >> 4) * 8 + j;
    int ch = ct * 16 + (l & 15);
    float val = 0.f;
    if (k < 528) {
      float s2 = g2[ch] * rsqrtf(v2[ch] + EPS);
      val = w2[ch * 528 + k] * s2;
    }
    w2f[t] = f2bf(val);
  }
  if (t < 8192) {   // w1f[c][m] = w1[m][c] * s1[m]
    int c = t >> 5, m = t & 31;
    float s1 = g1[m] * rsqrtf(v1[m] + EPS);
    w1f[t] = w1[m * 256 + c] * s1;
  }
  if (t < 32) {
    float s1 = g1[t] * rsqrtf(v1[t] + EPS);
    beta1[t] = (b1[t] - m1[t]) * s1 + be1[t];
  }
  if (t < 256) {
    float s2 = g2[t] * rsqrtf(v2[t] + EPS);
    beta2[t] = (b2[t] - m2[t]) * s2 + be2[t];
  }
}

// ---------------------------------------------------------------------------
// Layer 1: y[p][m] = relu(sum_c x[p][c]*w1f[c][m] + beta1[m]), bf16 out.
// 256 pixels/block, thread = pixel. x staged through double-buffered LDS
// ([32][257] pad -> conflict-free), w1f read wave-uniform (SGPR FMAs).
// ---------------------------------------------------------------------------
__global__ __launch_bounds__(256) void k_layer1(
    const float* __restrict__ x, const float* __restrict__ w1f,
    const float* __restrict__ beta1, unsigned short* __restrict__ yws)
{
  __shared__ float xs[2][32 * 257];
  int tid = threadIdx.x;
  int pb = blockIdx.x * 256;
  int b = pb >> 12;
  int hw0 = pb & 4095;
  const float* xb = x + ((size_t)b << 20);

  int c_l = tid >> 3, t8 = tid & 7;   // staging map: channel c_l, pixel chunk t8
  float4 rg[8];

  // stage chunk 0
#pragma unroll
  for (int i = 0; i < 8; ++i)
    rg[i] = *(const float4*)&xb[(size_t)c_l * 4096 + hw0 + t8 * 4 + i * 32];
#pragma unroll
  for (int i = 0; i < 8; ++i) {
    int base = c_l * 257 + t8 * 4 + i * 32;
    xs[0][base] = rg[i].x; xs[0][base + 1] = rg[i].y;
    xs[0][base + 2] = rg[i].z; xs[0][base + 3] = rg[i].w;
  }
  // issue chunk 1 loads
#pragma unroll
  for (int i = 0; i < 8; ++i)
    rg[i] = *(const float4*)&xb[(size_t)(32 + c_l) * 4096 + hw0 + t8 * 4 + i * 32];
  __syncthreads();

  float acc[32];
#pragma unroll
  for (int m = 0; m < 32; ++m) acc[m] = 0.f;

  for (int ch = 0; ch < 8; ++ch) {
    const float* xcur = xs[ch & 1];
    int cb = ch * 32;
#pragma unroll 4
    for (int ci = 0; ci < 32; ++ci) {
      float xv = xcur[ci * 257 + tid];
      const float* wrow = &w1f[(cb + ci) * 32];
#pragma unroll
      for (int m = 0; m < 32; ++m)
        acc[m] = fmaf(xv, wrow[m], acc[m]);
    }
    if (ch < 7) {
      __syncthreads();
      float* xn = xs[(ch + 1) & 1];
#pragma unroll
      for (int i = 0; i < 8; ++i) {
        int base = c_l * 257 + t8 * 4 + i * 32;
        xn[base] = rg[i].x; xn[base + 1] = rg[i].y;
        xn[base + 2] = rg[i].z; xn[base + 3] = rg[i].w;
      }
      if (ch + 2 < 8) {
#pragma unroll
        for (int i = 0; i < 8; ++i)
          rg[i] = *(const float4*)&xb[(size_t)((ch + 2) * 32 + c_l) * 4096 + hw0 + t8 * 4 + i * 32];
      }
      __syncthreads();
    }
  }

  int p = pb + tid;
  unsigned int outw[16];
#pragma unroll
  for (int m = 0; m < 16; ++m) {
    float a  = fmaxf(acc[2 * m]     + beta1[2 * m],     0.f);
    float bv = fmaxf(acc[2 * m + 1] + beta1[2 * m + 1], 0.f);
    outw[m] = (unsigned int)f2bf(a) | ((unsigned int)f2bf(bv) << 16);
  }
  uint4* dst = (uint4*)(yws + (size_t)p * 32);
#pragma unroll
  for (int q = 0; q < 4; ++q)
    dst[q] = make_uint4(outw[4 * q], outw[4 * q + 1], outw[4 * q + 2], outw[4 * q + 3]);
}

// ---------------------------------------------------------------------------
// Layer 2: per block 64 pixels x 256 channels.
//   A: y tile -> LDS (f32, [64][33])
//   B: packed[p][t] = y[p][rows[t]]*y[p][cols[t]] -> LDS bf16, stride 548
//   C: 17 K-steps x 16 mfma_f32_16x16x32_bf16 per wave, no barriers.
//      D[row=channel][col=pixel] -> coalesced f32 stores along hw.
// ---------------------------------------------------------------------------
__global__ __launch_bounds__(256) void k_layer2(
    const unsigned short* __restrict__ yws, const unsigned short* __restrict__ w2f,
    const float* __restrict__ beta2, float* __restrict__ out)
{
  __shared__ __align__(16) unsigned short pk[64 * 548];
  __shared__ float ylds[64 * 33];
  int tid = threadIdx.x;
  int wv = tid >> 6, lane = tid & 63;
  int pb = blockIdx.x * 64;
  int b = pb >> 12, hw0 = pb & 4095;

  // phase A: load y tile (64 pixels x 32 bf16 = 4KB)
  {
    const uint4* src = (const uint4*)(yws + (size_t)pb * 32);
    uint4 v = src[tid];
    int p = tid >> 2, m0 = (tid & 3) * 8;
    float* yrow = &ylds[p * 33 + m0];
    unsigned int ua[4] = {v.x, v.y, v.z, v.w};
#pragma unroll
    for (int q = 0; q < 4; ++q) {
      yrow[2 * q]     = bf2f((unsigned short)(ua[q] & 0xFFFFu));
      yrow[2 * q + 1] = bf2f((unsigned short)(ua[q] >> 16));
    }
  }
  __syncthreads();

  // phase B: packed bilinear products (diag order matches reference)
  {
    int p = lane;
    const float* yr = &ylds[p * 33];
    unsigned short* pr = &pk[p * 548];
    for (int i = wv; i < 32; i += 4) {
      int base = 32 * i - (i * (i - 1)) / 2;
      int len = 32 - i;
      for (int j = 0; j < len; ++j) {
        float prod = yr[i + j] * yr[j];
        pr[base + j] = f2bf(prod);
      }
    }
    if (wv == 0) {  // zero K-pad 528..547
      unsigned int* pru = (unsigned int*)pk + p * 274;
#pragma unroll
      for (int z = 264; z < 274; ++z) pru[z] = 0u;
    }
  }
  __syncthreads();

  // phase C: MFMA main loop
  f32x4 acc[4][4];
#pragma unroll
  for (int a = 0; a < 4; ++a)
#pragma unroll
    for (int c = 0; c < 4; ++c)
      acc[a][c] = (f32x4){0.f, 0.f, 0.f, 0.f};

  const uint4* w2f4 = (const uint4*)w2f;
  int l15 = lane & 15, l4 = lane >> 4;

  for (int ks = 0; ks < 17; ++ks) {
    union { uint4 q; bf16x8 v; } A[4], B[4];
#pragma unroll
    for (int ctl = 0; ctl < 4; ++ctl)
      A[ctl].q = w2f4[(ks * 16 + wv * 4 + ctl) * 64 + lane];
#pragma unroll
    for (int pt = 0; pt < 4; ++pt) {
      const unsigned short* src = &pk[(pt * 16 + l15) * 548 + ks * 32 + l4 * 8];
      uint2 lo = *(const uint2*)src;
      uint2 hi = *(const uint2*)(src + 4);
      B[pt].q = make_uint4(lo.x, lo.y, hi.x, hi.y);
    }
#pragma unroll
    for (int pt = 0; pt < 4; ++pt)
#pragma unroll
      for (int ctl = 0; ctl < 4; ++ctl)
        acc[pt][ctl] = __builtin_amdgcn_mfma_f32_16x16x32_bf16(
            A[ctl].v, B[pt].v, acc[pt][ctl], 0, 0, 0);
  }

  // epilogue: BN fold + relu, coalesced stores
  float bet[4][4];
#pragma unroll
  for (int ctl = 0; ctl < 4; ++ctl)
#pragma unroll
    for (int r = 0; r < 4; ++r)
      bet[ctl][r] = beta2[(wv * 4 + ctl) * 16 + l4 * 4 + r];

#pragma unroll
  for (int pt = 0; pt < 4; ++pt) {
    int hw = hw0 + pt * 16 + l15;
#pragma unroll
    for (int ctl = 0; ctl < 4; ++ctl) {
      int ch = (wv * 4 + ctl) * 16 + l4 * 4;
#pragma unroll
      for (int r = 0; r < 4; ++r) {
        float v = fmaxf(acc[pt][ctl][r] + bet[ctl][r], 0.f);
        out[(((size_t)b * 256 + (ch + r)) << 12) + hw] = v;
      }
    }
  }
}

// ---------------------------------------------------------------------------
extern "C" void kernel_launch(void* const* d_in, const int* in_sizes, int n_in,
                              void* d_out, int out_size, void* d_ws, size_t ws_size,
                              hipStream_t stream)
{
  const float* x   = (const float*)d_in[0];
  const float* w1  = (const float*)d_in[1];
  const float* b1  = (const float*)d_in[2];
  const float* g1  = (const float*)d_in[3];
  const float* be1 = (const float*)d_in[4];
  const float* m1  = (const float*)d_in[5];
  const float* v1  = (const float*)d_in[6];
  const float* w2  = (const float*)d_in[7];
  const float* b2  = (const float*)d_in[8];
  const float* g2  = (const float*)d_in[9];
  const float* be2 = (const float*)d_in[10];
  const float* m2  = (const float*)d_in[11];
  const float* v2  = (const float*)d_in[12];

  char* ws = (char*)d_ws;
  float*          w1f   = (float*)(ws);                 // 32768 B
  float*          beta1 = (float*)(ws + 32768);         // 128 B
  float*          beta2 = (float*)(ws + 32896);         // 1024 B
  unsigned short* w2f   = (unsigned short*)(ws + 33920);  // 278528 B
  unsigned short* yws   = (unsigned short*)(ws + 327680); // 4 MB
  float* out = (float*)d_out;

  k_prep<<<dim3(544), dim3(256), 0, stream>>>(
      w1, b1, g1, be1, m1, v1, w2, b2, g2, be2, m2, v2, w1f, beta1, beta2, w2f);
  k_layer1<<<dim3(256), dim3(256), 0, stream>>>(x, w1f, beta1, yws);
  k_layer2<<<dim3(1024), dim3(256), 0, stream>>>(yws, w2f, beta2, out);
}

// Round 2
// 57.635 us; speedup vs baseline: 1.6247x; 1.6247x over previous
//
#include <hip/hip_runtime.h>

#define EPS 1e-5f

typedef float f32x4 __attribute__((ext_vector_type(4)));
typedef short bf16x8 __attribute__((ext_vector_type(8)));

__device__ __forceinline__ unsigned short f2bf(float f) {
  unsigned int u = __builtin_bit_cast(unsigned int, f);
  u = (u + 0x7FFFu + ((u >> 16) & 1u)) >> 16;
  return (unsigned short)u;
}

// ---------------------------------------------------------------------------
// Prep: fold BN into weights; emit both weight matrices in MFMA A-fragment
// layout (bf16).  Frag element: idx = ((ks*CT + ct)*64 + lane)*8 + j
//   <-> A[ch = ct*16 + (lane&15)][k = ks*32 + (lane>>4)*8 + j]
// w2: K 528 -> 544 zero-padded (17 ks, CT=16).  w1: K=256 exact (8 ks, CT=2).
// ---------------------------------------------------------------------------
__global__ __launch_bounds__(256) void k_prep(
    const float* __restrict__ w1, const float* __restrict__ b1,
    const float* __restrict__ g1, const float* __restrict__ be1,
    const float* __restrict__ m1, const float* __restrict__ v1,
    const float* __restrict__ w2, const float* __restrict__ b2,
    const float* __restrict__ g2, const float* __restrict__ be2,
    const float* __restrict__ m2, const float* __restrict__ v2,
    float* __restrict__ beta1, float* __restrict__ beta2,
    unsigned short* __restrict__ w1b, unsigned short* __restrict__ w2f)
{
  int t = blockIdx.x * 256 + threadIdx.x;
  if (t < 139264) {   // w2 fragments: 17 ks * 16 ct * 64 lanes * 8
    int j = t & 7, l = (t >> 3) & 63, g = t >> 9;
    int ct = g & 15, ks = g >> 4;
    int k = ks * 32 + (l >> 4) * 8 + j;
    int ch = ct * 16 + (l & 15);
    float val = 0.f;
    if (k < 528) {
      float s2 = g2[ch] * rsqrtf(v2[ch] + EPS);
      val = w2[ch * 528 + k] * s2;
    }
    w2f[t] = f2bf(val);
  }
  if (t < 8192) {     // w1 fragments: 8 ks * 2 ct * 64 lanes * 8
    int j = t & 7, l = (t >> 3) & 63, g = t >> 9;
    int ct = g & 1, ks = g >> 1;
    int c = ks * 32 + (l >> 4) * 8 + j;
    int m = ct * 16 + (l & 15);
    float s1 = g1[m] * rsqrtf(v1[m] + EPS);
    w1b[t] = f2bf(w1[m * 256 + c] * s1);
  }
  if (t < 32) {
    float s1 = g1[t] * rsqrtf(v1[t] + EPS);
    beta1[t] = (b1[t] - m1[t]) * s1 + be1[t];
  }
  if (t < 256) {
    float s2 = g2[t] * rsqrtf(v2[t] + EPS);
    beta2[t] = (b2[t] - m2[t]) * s2 + be2[t];
  }
}

// ---------------------------------------------------------------------------
// Fused: per block, 64 pixels x full pipeline.
//  P0: stage x[256c][64p] -> LDS bf16 [px][ch], row stride 276 (b64-aligned)
//  P1: layer1 MFMA (8 ks x 2 ct per wave, wave owns 16 px) -> yf f32 LDS
//  P2: packed bilinear products -> pk bf16 LDS, row stride 548 (verified)
//  P3: layer2 MFMA (17 ks x 4 ct x 4 pt per wave) + BN/relu + stores
// LDS: pk 70144B (x-tile reuses its first 35328B) + yf 8448B = 78592B
//  -> 2 blocks/CU.
// ---------------------------------------------------------------------------
__global__ __launch_bounds__(256) void k_fused(
    const float* __restrict__ x, const unsigned short* __restrict__ w1b,
    const float* __restrict__ beta1, const unsigned short* __restrict__ w2f,
    const float* __restrict__ beta2, float* __restrict__ out)
{
  __shared__ __align__(16) unsigned short pk[64 * 548];
  __shared__ float yf[64 * 33];
  int tid = threadIdx.x;
  int wv = tid >> 6, lane = tid & 63;
  int l15 = lane & 15, l4 = lane >> 4;
  int pb = blockIdx.x * 64;
  int b = pb >> 12, hw0 = pb & 4095;
  const float* xb = x + ((size_t)b << 20) + hw0;

  // ---- P0: stage x -> bf16 transposed tile (row = px, stride 276 u16)
  unsigned short* xt = pk;   // first 35328B of pk
  {
    int q = tid & 15;        // px quad
    int c40 = tid >> 4;      // channel quad within pass
    for (int pass = 0; pass < 4; ++pass) {
      int c4 = c40 + pass * 16;   // ch = 4*c4 + i
      float4 v[4];
#pragma unroll
      for (int i = 0; i < 4; ++i)
        v[i] = *(const float4*)&xb[(size_t)(4 * c4 + i) * 4096 + 4 * q];
#pragma unroll
      for (int s = 0; s < 4; ++s) {   // s = px sub
        float e0 = ((const float*)&v[0])[s];
        float e1 = ((const float*)&v[1])[s];
        float e2 = ((const float*)&v[2])[s];
        float e3 = ((const float*)&v[3])[s];
        unsigned int lo = (unsigned int)f2bf(e0) | ((unsigned int)f2bf(e1) << 16);
        unsigned int hi = (unsigned int)f2bf(e2) | ((unsigned int)f2bf(e3) << 16);
        *(uint2*)&xt[(4 * q + s) * 276 + 4 * c4] = make_uint2(lo, hi);
      }
    }
  }
  __syncthreads();

  // ---- P1: layer1 MFMA.  Wave wv owns px = wv*16 + l15, all 32 m.
  {
    f32x4 acc1[2];
    acc1[0] = (f32x4){0.f, 0.f, 0.f, 0.f};
    acc1[1] = (f32x4){0.f, 0.f, 0.f, 0.f};
    const uint4* w1b4 = (const uint4*)w1b;
    int px = wv * 16 + l15;
    for (int ks = 0; ks < 8; ++ks) {
      union { uint4 q; bf16x8 v; } A0, A1, B;
      A0.q = w1b4[(ks * 2 + 0) * 64 + lane];
      A1.q = w1b4[(ks * 2 + 1) * 64 + lane];
      const unsigned short* s = &xt[px * 276 + ks * 32 + l4 * 8];
      uint2 lo = *(const uint2*)s;
      uint2 hi = *(const uint2*)(s + 4);
      B.q = make_uint4(lo.x, lo.y, hi.x, hi.y);
      acc1[0] = __builtin_amdgcn_mfma_f32_16x16x32_bf16(A0.v, B.v, acc1[0], 0, 0, 0);
      acc1[1] = __builtin_amdgcn_mfma_f32_16x16x32_bf16(A1.v, B.v, acc1[1], 0, 0, 0);
    }
    __syncthreads();   // xt fully consumed; pk region free for products
#pragma unroll
    for (int ct = 0; ct < 2; ++ct) {
      int m0 = ct * 16 + l4 * 4;
#pragma unroll
      for (int r = 0; r < 4; ++r) {
        float yv = fmaxf(acc1[ct][r] + beta1[m0 + r], 0.f);
        yf[px * 33 + m0 + r] = yv;
      }
    }
  }
  __syncthreads();

  // ---- P2: packed bilinear products (diag order), pair-packed b32 writes
  {
    int p2 = tid & 63, set = tid >> 6;
    const float* yr = &yf[p2 * 33];
    unsigned short* pr = &pk[p2 * 548];
    for (int i = set; i < 32; i += 4) {
      int base = 32 * i - (i * (i - 1)) / 2;
      int len = 32 - i;
      int j = 0;
      if (base & 1) {           // align to even t for b32 writes
        pr[base] = f2bf(yr[i] * yr[0]);
        j = 1;
      }
      for (; j + 1 < len; j += 2) {
        float a = yr[i + j] * yr[j];
        float c = yr[i + j + 1] * yr[j + 1];
        *(unsigned int*)&pr[base + j] =
            (unsigned int)f2bf(a) | ((unsigned int)f2bf(c) << 16);
      }
      if (j < len) pr[base + j] = f2bf(yr[i + j] * yr[j]);
    }
    if (tid < 64) {             // zero K-pad 528..547
      unsigned int* pru = (unsigned int*)pk + tid * 274;
#pragma unroll
      for (int z = 264; z < 274; ++z) pru[z] = 0u;
    }
  }
  __syncthreads();

  // ---- P3: layer2 MFMA.  Wave owns ct = wv*4..wv*4+3, all 4 pt.
  f32x4 acc[4][4];
#pragma unroll
  for (int a = 0; a < 4; ++a)
#pragma unroll
    for (int c = 0; c < 4; ++c)
      acc[a][c] = (f32x4){0.f, 0.f, 0.f, 0.f};

  const uint4* w2f4 = (const uint4*)w2f;
  for (int ks = 0; ks < 17; ++ks) {
    union { uint4 q; bf16x8 v; } A[4], B[4];
#pragma unroll
    for (int ctl = 0; ctl < 4; ++ctl)
      A[ctl].q = w2f4[(ks * 16 + wv * 4 + ctl) * 64 + lane];
#pragma unroll
    for (int pt = 0; pt < 4; ++pt) {
      const unsigned short* src = &pk[(pt * 16 + l15) * 548 + ks * 32 + l4 * 8];
      uint2 lo = *(const uint2*)src;
      uint2 hi = *(const uint2*)(src + 4);
      B[pt].q = make_uint4(lo.x, lo.y, hi.x, hi.y);
    }
#pragma unroll
    for (int pt = 0; pt < 4; ++pt)
#pragma unroll
      for (int ctl = 0; ctl < 4; ++ctl)
        acc[pt][ctl] = __builtin_amdgcn_mfma_f32_16x16x32_bf16(
            A[ctl].v, B[pt].v, acc[pt][ctl], 0, 0, 0);
  }

  // epilogue: BN fold + relu, coalesced stores (4 x 64B segments / instr)
  float bet[4][4];
#pragma unroll
  for (int ctl = 0; ctl < 4; ++ctl)
#pragma unroll
    for (int r = 0; r < 4; ++r)
      bet[ctl][r] = beta2[(wv * 4 + ctl) * 16 + l4 * 4 + r];

#pragma unroll
  for (int pt = 0; pt < 4; ++pt) {
    int hw = hw0 + pt * 16 + l15;
#pragma unroll
    for (int ctl = 0; ctl < 4; ++ctl) {
      int ch = (wv * 4 + ctl) * 16 + l4 * 4;
#pragma unroll
      for (int r = 0; r < 4; ++r) {
        float v = fmaxf(acc[pt][ctl][r] + bet[ctl][r], 0.f);
        out[(((size_t)b * 256 + (ch + r)) << 12) + hw] = v;
      }
    }
  }
}

// ---------------------------------------------------------------------------
extern "C" void kernel_launch(void* const* d_in, const int* in_sizes, int n_in,
                              void* d_out, int out_size, void* d_ws, size_t ws_size,
                              hipStream_t stream)
{
  const float* x   = (const float*)d_in[0];
  const float* w1  = (const float*)d_in[1];
  const float* b1  = (const float*)d_in[2];
  const float* g1  = (const float*)d_in[3];
  const float* be1 = (const float*)d_in[4];
  const float* m1  = (const float*)d_in[5];
  const float* v1  = (const float*)d_in[6];
  const float* w2  = (const float*)d_in[7];
  const float* b2  = (const float*)d_in[8];
  const float* g2  = (const float*)d_in[9];
  const float* be2 = (const float*)d_in[10];
  const float* m2  = (const float*)d_in[11];
  const float* v2  = (const float*)d_in[12];

  char* ws = (char*)d_ws;
  float*          beta1 = (float*)(ws);                  // 128 B
  float*          beta2 = (float*)(ws + 128);            // 1024 B
  unsigned short* w1b   = (unsigned short*)(ws + 1152);  // 16384 B
  unsigned short* w2f   = (unsigned short*)(ws + 17536); // 278528 B
  float* out = (float*)d_out;

  k_prep<<<dim3(544), dim3(256), 0, stream>>>(
      w1, b1, g1, be1, m1, v1, w2, b2, g2, be2, m2, v2, beta1, beta2, w1b, w2f);
  k_fused<<<dim3(1024), dim3(256), 0, stream>>>(x, w1b, beta1, w2f, beta2, out);
}

// Round 4
// 48.623 us; speedup vs baseline: 1.9259x; 1.1853x over previous
//
#include <hip/hip_runtime.h>

#define EPS 1e-5f

typedef float f32x4 __attribute__((ext_vector_type(4)));
typedef short bf16x8 __attribute__((ext_vector_type(8)));

__device__ __forceinline__ unsigned short f2bf(float f) {
  unsigned int u = __builtin_bit_cast(unsigned int, f);
  u = (u + 0x7FFFu + ((u >> 16) & 1u)) >> 16;
  return (unsigned short)u;
}

// ---------------------------------------------------------------------------
// Prep (identical to verified round-2): fold BN into weights; emit both
// weight matrices in MFMA A-fragment layout (bf16), REFERENCE k-order.
// Frag element: idx = ((ks*CT + ct)*64 + lane)*8 + j
//   <-> A[ch = ct*16 + (lane&15)][k = ks*32 + (lane>>4)*8 + j]
// w2: K 528 -> 544 zero-padded (17 ks, CT=16).  w1: K=256 exact (8 ks, CT=2).
// ---------------------------------------------------------------------------
__global__ __launch_bounds__(256) void k_prep(
    const float* __restrict__ w1, const float* __restrict__ b1,
    const float* __restrict__ g1, const float* __restrict__ be1,
    const float* __restrict__ m1, const float* __restrict__ v1,
    const float* __restrict__ w2, const float* __restrict__ b2,
    const float* __restrict__ g2, const float* __restrict__ be2,
    const float* __restrict__ m2, const float* __restrict__ v2,
    float* __restrict__ beta1, float* __restrict__ beta2,
    unsigned short* __restrict__ w1b, unsigned short* __restrict__ w2f)
{
  int t = blockIdx.x * 256 + threadIdx.x;
  if (t < 139264) {   // w2 fragments: 17 ks * 16 ct * 64 lanes * 8
    int j = t & 7, l = (t >> 3) & 63, g = t >> 9;
    int ct = g & 15, ks = g >> 4;
    int k = ks * 32 + (l >> 4) * 8 + j;
    int ch = ct * 16 + (l & 15);
    float val = 0.f;
    if (k < 528) {
      float s2 = g2[ch] * rsqrtf(v2[ch] + EPS);
      val = w2[ch * 528 + k] * s2;
    }
    w2f[t] = f2bf(val);
  }
  if (t < 8192) {     // w1 fragments: 8 ks * 2 ct * 64 lanes * 8
    int j = t & 7, l = (t >> 3) & 63, g = t >> 9;
    int ct = g & 1, ks = g >> 1;
    int c = ks * 32 + (l >> 4) * 8 + j;
    int m = ct * 16 + (l & 15);
    float s1 = g1[m] * rsqrtf(v1[m] + EPS);
    w1b[t] = f2bf(w1[m * 256 + c] * s1);
  }
  if (t < 32) {
    float s1 = g1[t] * rsqrtf(v1[t] + EPS);
    beta1[t] = (b1[t] - m1[t]) * s1 + be1[t];
  }
  if (t < 256) {
    float s2 = g2[t] * rsqrtf(v2[t] + EPS);
    beta2[t] = (b2[t] - m2[t]) * s2 + be2[t];
  }
}

// Write diag I (reference order, len 32-I at base(I)) from register y-row.
// All indexing static; paired b32 writes with compile-time parity handling.
template<int I>
__device__ __forceinline__ void do_diag(const float* __restrict__ y,
                                        unsigned short* __restrict__ pr)
{
  constexpr int L = 32 - I;
  constexpr int base = 32 * I - (I * (I - 1)) / 2;
  float p[L];
#pragma unroll
  for (int j = 0; j < L; ++j) p[j] = y[I + j] * y[j];
  constexpr int s = (base & 1) ? 1 : 0;
  if constexpr (s != 0) pr[base] = f2bf(p[0]);
#pragma unroll
  for (int j = s; j + 1 < L; j += 2)
    *(unsigned int*)&pr[base + j] =
        (unsigned int)f2bf(p[j]) | ((unsigned int)f2bf(p[j + 1]) << 16);
  if constexpr (((L - s) & 1) != 0) pr[base + L - 1] = f2bf(p[L - 1]);
}

// Balanced set: diags {S, 31-S, S+8, 23-S} = 66 products for every S.
template<int S>
__device__ __forceinline__ void do_set(const float* __restrict__ y,
                                       unsigned short* __restrict__ pr)
{
  do_diag<S>(y, pr);
  do_diag<31 - S>(y, pr);
  do_diag<S + 8>(y, pr);
  do_diag<23 - S>(y, pr);
}

// ---------------------------------------------------------------------------
// Fused, 32-pixel tiles (2048 blocks, 4 blocks/CU).
//  P0: x -> bf16 [px][276] tile (xt aliases pk)          (barrier)
//  P1: layer1 MFMA, 1 16x16 tile per wave -> yf f32 [px][34]   (barrier)
//  P2: y-row -> regs; static diag products -> pk (stride 548, ref order)
//  P3: layer2 MFMA 17 ks x 4 ct x 2 pt per wave + BN/relu + stores
// LDS: pk 35072B + yf 4352B = 39424B.
// ---------------------------------------------------------------------------
__global__ __launch_bounds__(256, 4) void k_fused(
    const float* __restrict__ x, const unsigned short* __restrict__ w1b,
    const float* __restrict__ beta1, const unsigned short* __restrict__ w2f,
    const float* __restrict__ beta2, float* __restrict__ out)
{
  __shared__ __align__(16) unsigned short pk[32 * 548];
  __shared__ __align__(8) float yf[32 * 34];
  int tid = threadIdx.x;
  int wv = tid >> 6, lane = tid & 63;
  int l15 = lane & 15, l4 = lane >> 4;
  int pb = blockIdx.x * 32;
  int b = pb >> 12, hw0 = pb & 4095;
  const float* xb = x + ((size_t)b << 20) + hw0;

  // ---- P0: stage x -> bf16 transposed tile (row = px, stride 276 u16)
  unsigned short* xt = pk;
  {
    int q = tid & 7;          // px quad (4*q .. 4*q+3)
    int cg = tid >> 3;        // channel-quad index within pass (0..31)
#pragma unroll
    for (int pass = 0; pass < 2; ++pass) {
      int c4 = cg + pass * 32;    // ch = 4*c4 + i
      float4 v[4];
#pragma unroll
      for (int i = 0; i < 4; ++i)
        v[i] = *(const float4*)&xb[(size_t)(4 * c4 + i) * 4096 + 4 * q];
#pragma unroll
      for (int s = 0; s < 4; ++s) {
        float e0 = ((const float*)&v[0])[s];
        float e1 = ((const float*)&v[1])[s];
        float e2 = ((const float*)&v[2])[s];
        float e3 = ((const float*)&v[3])[s];
        unsigned int lo = (unsigned int)f2bf(e0) | ((unsigned int)f2bf(e1) << 16);
        unsigned int hi = (unsigned int)f2bf(e2) | ((unsigned int)f2bf(e3) << 16);
        *(uint2*)&xt[(4 * q + s) * 276 + 4 * c4] = make_uint2(lo, hi);
      }
    }
  }
  __syncthreads();

  // ---- P1: layer1 MFMA; wave = (pxt = wv&1, mt = wv>>1) 16x16 tile
  {
    int pxt = wv & 1, mt = wv >> 1;
    int px = pxt * 16 + l15;
    f32x4 acc1 = (f32x4){0.f, 0.f, 0.f, 0.f};
    const uint4* w1b4 = (const uint4*)w1b;
    for (int ks = 0; ks < 8; ++ks) {
      union { uint4 q; bf16x8 v; } A, B;
      A.q = w1b4[(ks * 2 + mt) * 64 + lane];
      const unsigned short* s = &xt[px * 276 + ks * 32 + l4 * 8];
      uint2 lo = *(const uint2*)s;
      uint2 hi = *(const uint2*)(s + 4);
      B.q = make_uint4(lo.x, lo.y, hi.x, hi.y);
      acc1 = __builtin_amdgcn_mfma_f32_16x16x32_bf16(A.v, B.v, acc1, 0, 0, 0);
    }
    int m0 = mt * 16 + l4 * 4;
#pragma unroll
    for (int r = 0; r < 4; ++r)
      yf[px * 34 + m0 + r] = fmaxf(acc1[r] + beta1[m0 + r], 0.f);
  }
  __syncthreads();   // xt consumed AND yf ready; pk region free

  // ---- P2: register-sourced bilinear products, reference diag order
  {
    int px2 = tid & 31, set = tid >> 5;
    const float* yr = &yf[px2 * 34];
    unsigned short* pr = &pk[px2 * 548];
    float y[32];
#pragma unroll
    for (int k = 0; k < 16; ++k) {
      float2 v = *(const float2*)&yr[2 * k];
      y[2 * k] = v.x; y[2 * k + 1] = v.y;
    }
    switch (set) {
      case 0: do_set<0>(y, pr); break;
      case 1: do_set<1>(y, pr); break;
      case 2: do_set<2>(y, pr); break;
      case 3: do_set<3>(y, pr); break;
      case 4: do_set<4>(y, pr); break;
      case 5: do_set<5>(y, pr); break;
      case 6: do_set<6>(y, pr); break;
      default: do_set<7>(y, pr); break;
    }
    // zero K-pad slots 528..543 (16 shorts per pixel): sets 0..3 only
    if (set < 4) {
      *(unsigned int*)&pr[528 + set * 4] = 0u;
      *(unsigned int*)&pr[530 + set * 4] = 0u;
    }
  }
  __syncthreads();

  // ---- P3: layer2 MFMA.  Wave owns ct = wv*4..wv*4+3, pt = 0..1.
  f32x4 acc[2][4];
#pragma unroll
  for (int a = 0; a < 2; ++a)
#pragma unroll
    for (int c = 0; c < 4; ++c)
      acc[a][c] = (f32x4){0.f, 0.f, 0.f, 0.f};

  const uint4* w2f4 = (const uint4*)w2f;
  for (int ks = 0; ks < 17; ++ks) {
    union { uint4 q; bf16x8 v; } A[4], B[2];
#pragma unroll
    for (int ctl = 0; ctl < 4; ++ctl)
      A[ctl].q = w2f4[(ks * 16 + wv * 4 + ctl) * 64 + lane];
#pragma unroll
    for (int pt = 0; pt < 2; ++pt) {
      const unsigned short* src = &pk[(pt * 16 + l15) * 548 + ks * 32 + l4 * 8];
      uint2 lo = *(const uint2*)src;
      uint2 hi = *(const uint2*)(src + 4);
      B[pt].q = make_uint4(lo.x, lo.y, hi.x, hi.y);
    }
#pragma unroll
    for (int pt = 0; pt < 2; ++pt)
#pragma unroll
      for (int ctl = 0; ctl < 4; ++ctl)
        acc[pt][ctl] = __builtin_amdgcn_mfma_f32_16x16x32_bf16(
            A[ctl].v, B[pt].v, acc[pt][ctl], 0, 0, 0);
  }

  // ---- epilogue: BN fold + relu, coalesced stores
  float bet[4][4];
#pragma unroll
  for (int ctl = 0; ctl < 4; ++ctl)
#pragma unroll
    for (int r = 0; r < 4; ++r)
      bet[ctl][r] = beta2[(wv * 4 + ctl) * 16 + l4 * 4 + r];

#pragma unroll
  for (int pt = 0; pt < 2; ++pt) {
    int hw = hw0 + pt * 16 + l15;
#pragma unroll
    for (int ctl = 0; ctl < 4; ++ctl) {
      int ch = (wv * 4 + ctl) * 16 + l4 * 4;
#pragma unroll
      for (int r = 0; r < 4; ++r) {
        float v = fmaxf(acc[pt][ctl][r] + bet[ctl][r], 0.f);
        out[(((size_t)b * 256 + (ch + r)) << 12) + hw] = v;
      }
    }
  }
}

// ---------------------------------------------------------------------------
extern "C" void kernel_launch(void* const* d_in, const int* in_sizes, int n_in,
                              void* d_out, int out_size, void* d_ws, size_t ws_size,
                              hipStream_t stream)
{
  const float* x   = (const float*)d_in[0];
  const float* w1  = (const float*)d_in[1];
  const float* b1  = (const float*)d_in[2];
  const float* g1  = (const float*)d_in[3];
  const float* be1 = (const float*)d_in[4];
  const float* m1  = (const float*)d_in[5];
  const float* v1  = (const float*)d_in[6];
  const float* w2  = (const float*)d_in[7];
  const float* b2  = (const float*)d_in[8];
  const float* g2  = (const float*)d_in[9];
  const float* be2 = (const float*)d_in[10];
  const float* m2  = (const float*)d_in[11];
  const float* v2  = (const float*)d_in[12];

  char* ws = (char*)d_ws;
  float*          beta1 = (float*)(ws);                  // 128 B
  float*          beta2 = (float*)(ws + 128);            // 1024 B
  unsigned short* w1b   = (unsigned short*)(ws + 1152);  // 16384 B
  unsigned short* w2f   = (unsigned short*)(ws + 17536); // 278528 B
  float* out = (float*)d_out;

  k_prep<<<dim3(544), dim3(256), 0, stream>>>(
      w1, b1, g1, be1, m1, v1, w2, b2, g2, be2, m2, v2, beta1, beta2, w1b, w2f);
  k_fused<<<dim3(2048), dim3(256), 0, stream>>>(x, w1b, beta1, w2f, beta2, out);
}

// Round 5
// 48.440 us; speedup vs baseline: 1.9331x; 1.0038x over previous
//
#include <hip/hip_runtime.h>

#define EPS 1e-5f

typedef float f32x4 __attribute__((ext_vector_type(4)));
typedef short bf16x8 __attribute__((ext_vector_type(8)));

__device__ __forceinline__ unsigned short f2bf(float f) {
  unsigned int u = __builtin_bit_cast(unsigned int, f);
  u = (u + 0x7FFFu + ((u >> 16) & 1u)) >> 16;
  return (unsigned short)u;
}

// ---------------------------------------------------------------------------
// Prep (verified): fold BN into weights; emit both weight matrices in MFMA
// A-fragment layout (bf16), REFERENCE k-order.
// Frag element: idx = ((ks*CT + ct)*64 + lane)*8 + j
//   <-> A[ch = ct*16 + (lane&15)][k = ks*32 + (lane>>4)*8 + j]
// w2: K 528 -> 544 zero-padded (17 ks, CT=16).  w1: K=256 exact (8 ks, CT=2).
// ---------------------------------------------------------------------------
__global__ __launch_bounds__(256) void k_prep(
    const float* __restrict__ w1, const float* __restrict__ b1,
    const float* __restrict__ g1, const float* __restrict__ be1,
    const float* __restrict__ m1, const float* __restrict__ v1,
    const float* __restrict__ w2, const float* __restrict__ b2,
    const float* __restrict__ g2, const float* __restrict__ be2,
    const float* __restrict__ m2, const float* __restrict__ v2,
    float* __restrict__ beta1, float* __restrict__ beta2,
    unsigned short* __restrict__ w1b, unsigned short* __restrict__ w2f)
{
  int t = blockIdx.x * 256 + threadIdx.x;
  if (t < 139264) {   // w2 fragments: 17 ks * 16 ct * 64 lanes * 8
    int j = t & 7, l = (t >> 3) & 63, g = t >> 9;
    int ct = g & 15, ks = g >> 4;
    int k = ks * 32 + (l >> 4) * 8 + j;
    int ch = ct * 16 + (l & 15);
    float val = 0.f;
    if (k < 528) {
      float s2 = g2[ch] * rsqrtf(v2[ch] + EPS);
      val = w2[ch * 528 + k] * s2;
    }
    w2f[t] = f2bf(val);
  }
  if (t < 8192) {     // w1 fragments: 8 ks * 2 ct * 64 lanes * 8
    int j = t & 7, l = (t >> 3) & 63, g = t >> 9;
    int ct = g & 1, ks = g >> 1;
    int c = ks * 32 + (l >> 4) * 8 + j;
    int m = ct * 16 + (l & 15);
    float s1 = g1[m] * rsqrtf(v1[m] + EPS);
    w1b[t] = f2bf(w1[m * 256 + c] * s1);
  }
  if (t < 32) {
    float s1 = g1[t] * rsqrtf(v1[t] + EPS);
    beta1[t] = (b1[t] - m1[t]) * s1 + be1[t];
  }
  if (t < 256) {
    float s2 = g2[t] * rsqrtf(v2[t] + EPS);
    beta2[t] = (b2[t] - m2[t]) * s2 + be2[t];
  }
}

// Write diag I (reference order, len 32-I at base(I)) from register y-row.
template<int I>
__device__ __forceinline__ void do_diag(const float* __restrict__ y,
                                        unsigned short* __restrict__ pr)
{
  constexpr int L = 32 - I;
  constexpr int base = 32 * I - (I * (I - 1)) / 2;
  float p[L];
#pragma unroll
  for (int j = 0; j < L; ++j) p[j] = y[I + j] * y[j];
  constexpr int s = (base & 1) ? 1 : 0;
  if constexpr (s != 0) pr[base] = f2bf(p[0]);
#pragma unroll
  for (int j = s; j + 1 < L; j += 2)
    *(unsigned int*)&pr[base + j] =
        (unsigned int)f2bf(p[j]) | ((unsigned int)f2bf(p[j + 1]) << 16);
  if constexpr (((L - s) & 1) != 0) pr[base + L - 1] = f2bf(p[L - 1]);
}

// Balanced set: diags {S, 31-S, S+8, 23-S} = 66 products for every S.
template<int S>
__device__ __forceinline__ void do_set(const float* __restrict__ y,
                                       unsigned short* __restrict__ pr)
{
  do_diag<S>(y, pr);
  do_diag<31 - S>(y, pr);
  do_diag<S + 8>(y, pr);
  do_diag<23 - S>(y, pr);
}

// ---------------------------------------------------------------------------
// Fused, 32-pixel tiles (2048 blocks, 4 blocks/CU).
//  P0: x -> bf16 [px][276] tile (xt aliases pk)              (barrier)
//  P1: layer1 MFMA (unrolled) -> yf f32 [px][34]             (barrier)
//  P2: y-row -> regs; static diag products -> pk              (barrier)
//  P3: layer2 MFMA, FULL UNROLL + depth-2 A-prefetch, + BN/relu + stores
// LDS: pk 35072B + yf 4352B = 39424B.
// ---------------------------------------------------------------------------
__global__ __launch_bounds__(256, 4) void k_fused(
    const float* __restrict__ x, const unsigned short* __restrict__ w1b,
    const float* __restrict__ beta1, const unsigned short* __restrict__ w2f,
    const float* __restrict__ beta2, float* __restrict__ out)
{
  __shared__ __align__(16) unsigned short pk[32 * 548];
  __shared__ __align__(8) float yf[32 * 34];
  int tid = threadIdx.x;
  int wv = tid >> 6, lane = tid & 63;
  int l15 = lane & 15, l4 = lane >> 4;
  int pb = blockIdx.x * 32;
  int b = pb >> 12, hw0 = pb & 4095;
  const float* xb = x + ((size_t)b << 20) + hw0;

  // ---- P0: stage x -> bf16 transposed tile (row = px, stride 276 u16)
  unsigned short* xt = pk;
  {
    int q = tid & 7;          // px quad (4*q .. 4*q+3)
    int cg = tid >> 3;        // channel-quad index within pass (0..31)
#pragma unroll
    for (int pass = 0; pass < 2; ++pass) {
      int c4 = cg + pass * 32;    // ch = 4*c4 + i
      float4 v[4];
#pragma unroll
      for (int i = 0; i < 4; ++i)
        v[i] = *(const float4*)&xb[(size_t)(4 * c4 + i) * 4096 + 4 * q];
#pragma unroll
      for (int s = 0; s < 4; ++s) {
        float e0 = ((const float*)&v[0])[s];
        float e1 = ((const float*)&v[1])[s];
        float e2 = ((const float*)&v[2])[s];
        float e3 = ((const float*)&v[3])[s];
        unsigned int lo = (unsigned int)f2bf(e0) | ((unsigned int)f2bf(e1) << 16);
        unsigned int hi = (unsigned int)f2bf(e2) | ((unsigned int)f2bf(e3) << 16);
        *(uint2*)&xt[(4 * q + s) * 276 + 4 * c4] = make_uint2(lo, hi);
      }
    }
  }
  __syncthreads();

  // ---- P1: layer1 MFMA; wave = (pxt = wv&1, mt = wv>>1) 16x16 tile
  {
    int pxt = wv & 1, mt = wv >> 1;
    int px = pxt * 16 + l15;
    f32x4 acc1 = (f32x4){0.f, 0.f, 0.f, 0.f};
    const uint4* w1b4 = (const uint4*)w1b;
#pragma unroll
    for (int ks = 0; ks < 8; ++ks) {
      union { uint4 q; bf16x8 v; } A, B;
      A.q = w1b4[(ks * 2 + mt) * 64 + lane];
      const unsigned short* s = &xt[px * 276 + ks * 32 + l4 * 8];
      uint2 lo = *(const uint2*)s;
      uint2 hi = *(const uint2*)(s + 4);
      B.q = make_uint4(lo.x, lo.y, hi.x, hi.y);
      acc1 = __builtin_amdgcn_mfma_f32_16x16x32_bf16(A.v, B.v, acc1, 0, 0, 0);
    }
    int m0 = mt * 16 + l4 * 4;
#pragma unroll
    for (int r = 0; r < 4; ++r)
      yf[px * 34 + m0 + r] = fmaxf(acc1[r] + beta1[m0 + r], 0.f);
  }
  __syncthreads();   // xt consumed AND yf ready; pk region free

  // ---- P2: register-sourced bilinear products, reference diag order
  {
    int px2 = tid & 31, set = tid >> 5;
    const float* yr = &yf[px2 * 34];
    unsigned short* pr = &pk[px2 * 548];
    float y[32];
#pragma unroll
    for (int k = 0; k < 16; ++k) {
      float2 v = *(const float2*)&yr[2 * k];
      y[2 * k] = v.x; y[2 * k + 1] = v.y;
    }
    switch (set) {
      case 0: do_set<0>(y, pr); break;
      case 1: do_set<1>(y, pr); break;
      case 2: do_set<2>(y, pr); break;
      case 3: do_set<3>(y, pr); break;
      case 4: do_set<4>(y, pr); break;
      case 5: do_set<5>(y, pr); break;
      case 6: do_set<6>(y, pr); break;
      default: do_set<7>(y, pr); break;
    }
    // zero K-pad slots 528..543 (16 shorts per pixel): sets 0..3 only
    if (set < 4) {
      *(unsigned int*)&pr[528 + set * 4] = 0u;
      *(unsigned int*)&pr[530 + set * 4] = 0u;
    }
  }

  // beta2 loads issued before the barrier so their latency hides under P3
  float bet[4][4];
#pragma unroll
  for (int ctl = 0; ctl < 4; ++ctl)
#pragma unroll
    for (int r = 0; r < 4; ++r)
      bet[ctl][r] = beta2[(wv * 4 + ctl) * 16 + l4 * 4 + r];

  __syncthreads();

  // ---- P3: layer2 MFMA, full unroll, rotating depth-2 A-prefetch.
  f32x4 acc[2][4];
#pragma unroll
  for (int a = 0; a < 2; ++a)
#pragma unroll
    for (int c = 0; c < 4; ++c)
      acc[a][c] = (f32x4){0.f, 0.f, 0.f, 0.f};

  const uint4* w2f4 = (const uint4*)w2f;
  int wbase = wv * 4;
  uint4 Apre[3][4];
#pragma unroll
  for (int ctl = 0; ctl < 4; ++ctl)
    Apre[0][ctl] = w2f4[(0 * 16 + wbase + ctl) * 64 + lane];
#pragma unroll
  for (int ctl = 0; ctl < 4; ++ctl)
    Apre[1][ctl] = w2f4[(1 * 16 + wbase + ctl) * 64 + lane];

#pragma unroll
  for (int ks = 0; ks < 17; ++ks) {
    if (ks + 2 < 17) {
#pragma unroll
      for (int ctl = 0; ctl < 4; ++ctl)
        Apre[(ks + 2) % 3][ctl] = w2f4[((ks + 2) * 16 + wbase + ctl) * 64 + lane];
    }
    union { uint4 q; bf16x8 v; } B[2];
#pragma unroll
    for (int pt = 0; pt < 2; ++pt) {
      const unsigned short* src = &pk[(pt * 16 + l15) * 548 + ks * 32 + l4 * 8];
      uint2 lo = *(const uint2*)src;
      uint2 hi = *(const uint2*)(src + 4);
      B[pt].q = make_uint4(lo.x, lo.y, hi.x, hi.y);
    }
#pragma unroll
    for (int pt = 0; pt < 2; ++pt)
#pragma unroll
      for (int ctl = 0; ctl < 4; ++ctl) {
        union { uint4 q; bf16x8 v; } Au;
        Au.q = Apre[ks % 3][ctl];
        acc[pt][ctl] = __builtin_amdgcn_mfma_f32_16x16x32_bf16(
            Au.v, B[pt].v, acc[pt][ctl], 0, 0, 0);
      }
  }

  // ---- epilogue: BN fold + relu, coalesced stores
#pragma unroll
  for (int pt = 0; pt < 2; ++pt) {
    int hw = hw0 + pt * 16 + l15;
#pragma unroll
    for (int ctl = 0; ctl < 4; ++ctl) {
      int ch = (wv * 4 + ctl) * 16 + l4 * 4;
#pragma unroll
      for (int r = 0; r < 4; ++r) {
        float v = fmaxf(acc[pt][ctl][r] + bet[ctl][r], 0.f);
        out[(((size_t)b * 256 + (ch + r)) << 12) + hw] = v;
      }
    }
  }
}

// ---------------------------------------------------------------------------
extern "C" void kernel_launch(void* const* d_in, const int* in_sizes, int n_in,
                              void* d_out, int out_size, void* d_ws, size_t ws_size,
                              hipStream_t stream)
{
  const float* x   = (const float*)d_in[0];
  const float* w1  = (const float*)d_in[1];
  const float* b1  = (const float*)d_in[2];
  const float* g1  = (const float*)d_in[3];
  const float* be1 = (const float*)d_in[4];
  const float* m1  = (const float*)d_in[5];
  const float* v1  = (const float*)d_in[6];
  const float* w2  = (const float*)d_in[7];
  const float* b2  = (const float*)d_in[8];
  const float* g2  = (const float*)d_in[9];
  const float* be2 = (const float*)d_in[10];
  const float* m2  = (const float*)d_in[11];
  const float* v2  = (const float*)d_in[12];

  char* ws = (char*)d_ws;
  float*          beta1 = (float*)(ws);                  // 128 B
  float*          beta2 = (float*)(ws + 128);            // 1024 B
  unsigned short* w1b   = (unsigned short*)(ws + 1152);  // 16384 B
  unsigned short* w2f   = (unsigned short*)(ws + 17536); // 278528 B
  float* out = (float*)d_out;

  k_prep<<<dim3(544), dim3(256), 0, stream>>>(
      w1, b1, g1, be1, m1, v1, w2, b2, g2, be2, m2, v2, beta1, beta2, w1b, w2f);
  k_fused<<<dim3(2048), dim3(256), 0, stream>>>(x, w1b, beta1, w2f, beta2, out);
}